// Round 2
// baseline (352.231 us; speedup 1.0000x reference)
//
#include <hip/hip_runtime.h>

typedef __bf16 bf16_t;
typedef __bf16 bf16x8 __attribute__((ext_vector_type(8)));
typedef float f32x4 __attribute__((ext_vector_type(4)));

#define NH 8
#define DH 32
#define QL 256
#define KL 256
#define CIN 64
#define HD 256  // NH*DH

__device__ __forceinline__ bf16_t f2bf(float x) { return (bf16_t)x; }

__device__ __forceinline__ f32x4 mfma16(bf16x8 a, bf16x8 b, f32x4 c) {
    return __builtin_amdgcn_mfma_f32_16x16x32_bf16(a, b, c, 0, 0, 0);
}

__device__ __forceinline__ bf16x8 cvt8(const float* __restrict__ p) {
    bf16x8 r;
#pragma unroll
    for (int j = 0; j < 8; ++j) r[j] = f2bf(p[j]);
    return r;
}

// grid (2, 128): block = (q-half bq, s). 256 thr = 4 waves.
// Wave w owns q rows [bq*128 + w*32, +32) and k/v rows [w*64, +64).
// Per head h: project q/k/v (bf16 MFMA), attention with softmax, then
// accumulate O_h @ wo_h into per-lane f32 regs. No workspace, no 2nd kernel.
__launch_bounds__(256, 1)
__global__ void attn_fused(const float* __restrict__ Xq,
                           const float* __restrict__ Xkv,
                           const float* __restrict__ Mask,
                           const float* __restrict__ Bias,
                           const float* __restrict__ Wq,
                           const float* __restrict__ Wk,
                           const float* __restrict__ Wv,
                           const float* __restrict__ Wo,
                           const float* __restrict__ Bo,
                           float* __restrict__ Out) {
    const int bq   = blockIdx.x;
    const int s    = blockIdx.y;
    const int tid  = threadIdx.x;
    const int lane = tid & 63;
    const int w    = tid >> 6;
    const int quad = lane >> 4;
    const int l16  = lane & 15;

    // 59.5 KB total (< 64 KB). Row strides are odd multiples of 8 bf16:
    // 16B-aligned for ds_read_b128, non-pow2 for bank spread.
    __shared__ __attribute__((aligned(16))) bf16_t sK[KL][DH + 8];      // 20480 B
    __shared__ __attribute__((aligned(16))) bf16_t sVT[DH][KL + 8];     // 16896 B
    __shared__ __attribute__((aligned(16))) bf16_t sP[4][16][128 + 8];  // 17408 B
    __shared__ __attribute__((aligned(16))) bf16_t sQs[4][16][DH + 8];  //  5120 B
    __shared__ float sMask[KL];                                         //  1024 B

    for (int i = tid; i < KL; i += 256)
        sMask[i] = (Mask[s * KL + i] - 1.0f) * 1.0e9f;

    const float scale = 0.17677669529663687f;  // 1/sqrt(32)
    const f32x4 vzero = {0.f, 0.f, 0.f, 0.f};

    f32x4 oacc[2][4];
#pragma unroll
    for (int i = 0; i < 2; ++i)
#pragma unroll
        for (int nt = 0; nt < 4; ++nt) oacc[i][nt] = vzero;

#pragma unroll 1
    for (int h = 0; h < NH; ++h) {
        // prior head's attention reads of sK/sVT must finish before overwrite
        // (h=0: publishes sMask)
        __syncthreads();

        // ---- B-fragments of this head's projection weights ----
        // B[k][n]: k = ks*32 + quad*8 + j, n = l16 (per 16-col n-tile)
        bf16x8 bwq[2][2], bwk[2][2], bwv[2][2];
#pragma unroll
        for (int nt = 0; nt < 2; ++nt)
#pragma unroll
            for (int ks = 0; ks < 2; ++ks) {
                bf16x8 fq, fk, fv;
#pragma unroll
                for (int j = 0; j < 8; ++j) {
                    const int kk = ks * 32 + quad * 8 + j;
                    const int cc = h * DH + nt * 16 + l16;
                    fq[j] = f2bf(Wq[kk * HD + cc]);
                    fk[j] = f2bf(Wk[kk * HD + cc]);
                    fv[j] = f2bf(Wv[kk * HD + cc]);
                }
                bwq[nt][ks] = fq;
                bwk[nt][ks] = fk;
                bwv[nt][ks] = fv;
            }
        // wo_h B-frags: B[k=quad*8+j][n=nt*16+l16] = Wo[(h*32+k)*64 + n]
        bf16x8 bwo[4];
#pragma unroll
        for (int nt = 0; nt < 4; ++nt) {
            bf16x8 f;
#pragma unroll
            for (int j = 0; j < 8; ++j)
                f[j] = f2bf(Wo[(h * DH + quad * 8 + j) * CIN + nt * 16 + l16]);
            bwo[nt] = f;
        }

        // ---- q projection -> A-frags in regs (per-wave LDS round-trip) ----
        bf16x8 aq[2];
#pragma unroll
        for (int i = 0; i < 2; ++i) {
            const int r0 = bq * 128 + w * 32 + i * 16;
            const float* xp = &Xq[(s * QL + r0 + l16) * CIN + quad * 8];
            const bf16x8 a0 = cvt8(xp);
            const bf16x8 a1 = cvt8(xp + 32);
            f32x4 c0 = vzero, c1 = vzero;
            c0 = mfma16(a0, bwq[0][0], c0);
            c0 = mfma16(a1, bwq[0][1], c0);
            c1 = mfma16(a0, bwq[1][0], c1);
            c1 = mfma16(a1, bwq[1][1], c1);
            // C/D layout: row = quad*4+r, col = l16 (per n-tile)
#pragma unroll
            for (int nt = 0; nt < 2; ++nt) {
                const f32x4 c = nt ? c1 : c0;
#pragma unroll
                for (int r = 0; r < 4; ++r)
                    sQs[w][quad * 4 + r][nt * 16 + l16] = f2bf(c[r] * scale);
            }
            // same-wave DS ops are in-order: read sees the writes above
            aq[i] = *(const bf16x8*)&sQs[w][l16][quad * 8];
        }

        // ---- k, v projections -> sK, sVT (wave rows [w*64, +64)) ----
#pragma unroll
        for (int t = 0; t < 4; ++t) {
            const int r0 = w * 64 + t * 16;
            const float* xp = &Xkv[(s * KL + r0 + l16) * CIN + quad * 8];
            const bf16x8 a0 = cvt8(xp);
            const bf16x8 a1 = cvt8(xp + 32);
            f32x4 k0 = vzero, k1 = vzero, v0 = vzero, v1 = vzero;
            k0 = mfma16(a0, bwk[0][0], k0);
            k0 = mfma16(a1, bwk[0][1], k0);
            k1 = mfma16(a0, bwk[1][0], k1);
            k1 = mfma16(a1, bwk[1][1], k1);
            v0 = mfma16(a0, bwv[0][0], v0);
            v0 = mfma16(a1, bwv[0][1], v0);
            v1 = mfma16(a0, bwv[1][0], v1);
            v1 = mfma16(a1, bwv[1][1], v1);
#pragma unroll
            for (int nt = 0; nt < 2; ++nt) {
                const f32x4 kc = nt ? k1 : k0;
                const f32x4 vc = nt ? v1 : v0;
#pragma unroll
                for (int r = 0; r < 4; ++r) {
                    const int row = r0 + quad * 4 + r;
                    sK[row][nt * 16 + l16]  = f2bf(kc[r]);
                    sVT[nt * 16 + l16][row] = f2bf(vc[r]);  // V transposed: sVT[d][kv]
                }
            }
        }
        __syncthreads();

        // ---- attention, one 16-row m-tile at a time ----
#pragma unroll 1
        for (int i = 0; i < 2; ++i) {
            const int qr0 = bq * 128 + w * 32 + i * 16;
            f32x4 sv[16];
#pragma unroll
            for (int ct = 0; ct < 16; ++ct) {
                const bf16x8 bk = *(const bf16x8*)&sK[ct * 16 + l16][quad * 8];
                sv[ct] = mfma16(aq[i], bk, vzero);
            }
#pragma unroll
            for (int ct = 0; ct < 16; ++ct) {
                const float mterm = sMask[ct * 16 + l16];
                const float* bp = &Bias[(h * QL + qr0 + quad * 4) * KL + ct * 16 + l16];
#pragma unroll
                for (int r = 0; r < 4; ++r)
                    sv[ct][r] += bp[r * KL] + mterm;
            }
            // softmax: rows live on the 16-lane group (fixed quad); xor 1,2,4,8
            float mx[4] = {-1e30f, -1e30f, -1e30f, -1e30f};
#pragma unroll
            for (int ct = 0; ct < 16; ++ct)
#pragma unroll
                for (int r = 0; r < 4; ++r) mx[r] = fmaxf(mx[r], sv[ct][r]);
#pragma unroll
            for (int off = 1; off < 16; off <<= 1)
#pragma unroll
                for (int r = 0; r < 4; ++r) mx[r] = fmaxf(mx[r], __shfl_xor(mx[r], off, 64));
            float sum[4] = {0.f, 0.f, 0.f, 0.f};
#pragma unroll
            for (int ct = 0; ct < 16; ++ct)
#pragma unroll
                for (int r = 0; r < 4; ++r) {
                    const float e = __expf(sv[ct][r] - mx[r]);
                    sv[ct][r] = e;
                    sum[r] += e;
                }
#pragma unroll
            for (int off = 1; off < 16; off <<= 1)
#pragma unroll
                for (int r = 0; r < 4; ++r) sum[r] += __shfl_xor(sum[r], off, 64);

            // ---- PV in two 128-col halves via sP (C-layout -> A-layout) ----
            f32x4 o0 = vzero, o1 = vzero;
#pragma unroll
            for (int hf = 0; hf < 2; ++hf) {
#pragma unroll
                for (int c2 = 0; c2 < 8; ++c2) {
                    const int ct = hf * 8 + c2;
#pragma unroll
                    for (int r = 0; r < 4; ++r)
                        sP[w][quad * 4 + r][c2 * 16 + l16] = f2bf(sv[ct][r]);
                }
#pragma unroll
                for (int ks = 0; ks < 4; ++ks) {
                    const bf16x8 ap  = *(const bf16x8*)&sP[w][l16][ks * 32 + quad * 8];
                    const int kg     = hf * 128 + ks * 32 + quad * 8;
                    const bf16x8 bv0 = *(const bf16x8*)&sVT[l16][kg];
                    const bf16x8 bv1 = *(const bf16x8*)&sVT[16 + l16][kg];
                    o0 = mfma16(ap, bv0, o0);
                    o1 = mfma16(ap, bv1, o1);
                }
            }
            float rs[4];
#pragma unroll
            for (int r = 0; r < 4; ++r) rs[r] = 1.0f / sum[r];

            // ---- normalized O_h tile -> A-frag -> accumulate O_h @ wo_h ----
#pragma unroll
            for (int nt = 0; nt < 2; ++nt) {
                const f32x4 o = nt ? o1 : o0;
#pragma unroll
                for (int r = 0; r < 4; ++r)
                    sQs[w][quad * 4 + r][nt * 16 + l16] = f2bf(o[r] * rs[r]);
            }
            const bf16x8 ao = *(const bf16x8*)&sQs[w][l16][quad * 8];
#pragma unroll
            for (int nt = 0; nt < 4; ++nt)
                oacc[i][nt] = mfma16(ao, bwo[nt], oacc[i][nt]);
        }
    }

    // ---- epilogue: out = oacc + bo (fp32 writes) ----
#pragma unroll
    for (int i = 0; i < 2; ++i) {
        const int qr0 = bq * 128 + w * 32 + i * 16;
#pragma unroll
        for (int nt = 0; nt < 4; ++nt) {
            const float bo = Bo[nt * 16 + l16];
#pragma unroll
            for (int r = 0; r < 4; ++r)
                Out[(s * QL + qr0 + quad * 4 + r) * CIN + nt * 16 + l16] = oacc[i][nt][r] + bo;
        }
    }
}

extern "C" void kernel_launch(void* const* d_in, const int* in_sizes, int n_in,
                              void* d_out, int out_size, void* d_ws, size_t ws_size,
                              hipStream_t stream) {
    const float* Xq   = (const float*)d_in[0];
    const float* Xkv  = (const float*)d_in[1];
    const float* Mask = (const float*)d_in[2];
    const float* Bias = (const float*)d_in[3];
    const float* Wq   = (const float*)d_in[4];
    const float* Wk   = (const float*)d_in[5];
    const float* Wv   = (const float*)d_in[6];
    const float* Wo   = (const float*)d_in[7];
    const float* Bo   = (const float*)d_in[8];
    float* Out = (float*)d_out;

    attn_fused<<<dim3(2, 128), 256, 0, stream>>>(Xq, Xkv, Mask, Bias, Wq, Wk, Wv, Wo, Bo, Out);
}

// Round 3
// 250.769 us; speedup vs baseline: 1.4046x; 1.4046x over previous
//
#include <hip/hip_runtime.h>

typedef __bf16 bf16_t;
typedef __bf16 bf16x8 __attribute__((ext_vector_type(8)));
typedef float f32x4 __attribute__((ext_vector_type(4)));

#define NH 8
#define DH 32
#define QL 256
#define KL 256
#define CIN 64
#define HD 256  // NH*DH

__device__ __forceinline__ bf16_t f2bf(float x) { return (bf16_t)x; }

__device__ __forceinline__ f32x4 mfma16(bf16x8 a, bf16x8 b, f32x4 c) {
    return __builtin_amdgcn_mfma_f32_16x16x32_bf16(a, b, c, 0, 0, 0);
}

__device__ __forceinline__ bf16x8 cvt8(const float* __restrict__ p) {
    bf16x8 r;
#pragma unroll
    for (int j = 0; j < 8; ++j) r[j] = f2bf(p[j]);
    return r;
}

// One block per (h, s): 1024 blocks, 256 thr = 4 waves.
// Wave w owns q rows [w*64, +64) and k/v rows [w*64, +64).
// Projects q/k/v for head h, attention+softmax, writes normalized O_h (bf16)
// to Ows[(s*QL+q)*HD + h*DH + d]. Output projection is a second kernel.
__launch_bounds__(256, 3)
__global__ void attn_h(const float* __restrict__ Xq,
                       const float* __restrict__ Xkv,
                       const float* __restrict__ Mask,
                       const float* __restrict__ Bias,
                       const float* __restrict__ Wq,
                       const float* __restrict__ Wk,
                       const float* __restrict__ Wv,
                       bf16_t* __restrict__ Ows) {
    const int h    = blockIdx.x;
    const int s    = blockIdx.y;
    const int tid  = threadIdx.x;
    const int lane = tid & 63;
    const int w    = tid >> 6;
    const int quad = lane >> 4;
    const int l16  = lane & 15;

    // 50.5 KB total -> 3 blocks/CU (160/50.5). Row strides: odd multiples of
    // 8 bf16 (16B-aligned for ds_read_b128, non-pow2 bank spread).
    __shared__ __attribute__((aligned(16))) bf16_t sK[KL][DH + 8];     // 20480 B
    __shared__ __attribute__((aligned(16))) bf16_t sVT[DH][KL + 8];    // 16896 B
    __shared__ __attribute__((aligned(16))) bf16_t sP[4][16][64 + 8];  //  9216 B
    __shared__ __attribute__((aligned(16))) bf16_t sQs[4][16][DH + 8]; //  5120 B

    const float scale = 0.17677669529663687f;  // 1/sqrt(32)
    const f32x4 vzero = {0.f, 0.f, 0.f, 0.f};

    // mask term per lane: col = ct*16 + l16 (same for all quads/rows)
    float mterm[16];
#pragma unroll
    for (int ct = 0; ct < 16; ++ct)
        mterm[ct] = (Mask[s * KL + ct * 16 + l16] - 1.0f) * 1.0e9f;

    // ---- this head's projection-weight B-fragments (once per block) ----
    // B[k][n]: k = ks*32 + quad*8 + j, n = l16 (per 16-col n-tile)
    bf16x8 bwq[2][2], bwk[2][2], bwv[2][2];
#pragma unroll
    for (int nt = 0; nt < 2; ++nt)
#pragma unroll
        for (int ks = 0; ks < 2; ++ks) {
            bf16x8 fq, fk, fv;
#pragma unroll
            for (int j = 0; j < 8; ++j) {
                const int kk = ks * 32 + quad * 8 + j;
                const int cc = h * DH + nt * 16 + l16;
                fq[j] = f2bf(Wq[kk * HD + cc]);
                fk[j] = f2bf(Wk[kk * HD + cc]);
                fv[j] = f2bf(Wv[kk * HD + cc]);
            }
            bwq[nt][ks] = fq;
            bwk[nt][ks] = fk;
            bwv[nt][ks] = fv;
        }

    // ---- q projection -> A-frags in regs (per-wave LDS round-trip) ----
    bf16x8 aq[4];
#pragma unroll
    for (int i = 0; i < 4; ++i) {
        const int r0 = w * 64 + i * 16;
        const float* xp = &Xq[(s * QL + r0 + l16) * CIN + quad * 8];
        const bf16x8 a0 = cvt8(xp);
        const bf16x8 a1 = cvt8(xp + 32);
        f32x4 c0 = vzero, c1 = vzero;
        c0 = mfma16(a0, bwq[0][0], c0);
        c0 = mfma16(a1, bwq[0][1], c0);
        c1 = mfma16(a0, bwq[1][0], c1);
        c1 = mfma16(a1, bwq[1][1], c1);
        // C/D layout: row = quad*4+r, col = l16 (per n-tile)
#pragma unroll
        for (int nt = 0; nt < 2; ++nt) {
            const f32x4 c = nt ? c1 : c0;
#pragma unroll
            for (int r = 0; r < 4; ++r)
                sQs[w][quad * 4 + r][nt * 16 + l16] = f2bf(c[r] * scale);
        }
        // same-wave DS ops are in-order: this read sees the writes above
        aq[i] = *(const bf16x8*)&sQs[w][l16][quad * 8];
    }

    // ---- k, v projections -> sK, sVT (wave rows [w*64, +64)) ----
#pragma unroll
    for (int t = 0; t < 4; ++t) {
        const int r0 = w * 64 + t * 16;
        const float* xp = &Xkv[(s * KL + r0 + l16) * CIN + quad * 8];
        const bf16x8 a0 = cvt8(xp);
        const bf16x8 a1 = cvt8(xp + 32);
        f32x4 k0 = vzero, k1 = vzero, v0 = vzero, v1 = vzero;
        k0 = mfma16(a0, bwk[0][0], k0);
        k0 = mfma16(a1, bwk[0][1], k0);
        k1 = mfma16(a0, bwk[1][0], k1);
        k1 = mfma16(a1, bwk[1][1], k1);
        v0 = mfma16(a0, bwv[0][0], v0);
        v0 = mfma16(a1, bwv[0][1], v0);
        v1 = mfma16(a0, bwv[1][0], v1);
        v1 = mfma16(a1, bwv[1][1], v1);
#pragma unroll
        for (int nt = 0; nt < 2; ++nt) {
            const f32x4 kc = nt ? k1 : k0;
            const f32x4 vc = nt ? v1 : v0;
#pragma unroll
            for (int r = 0; r < 4; ++r) {
                const int row = r0 + quad * 4 + r;
                sK[row][nt * 16 + l16]  = f2bf(kc[r]);
                sVT[nt * 16 + l16][row] = f2bf(vc[r]);  // V transposed: sVT[d][kv]
            }
        }
    }
    __syncthreads();

    // ---- attention: 4 m-tiles per wave ----
#pragma unroll 1
    for (int i = 0; i < 4; ++i) {
        const int qr0 = w * 64 + i * 16;
        f32x4 sv[16];
#pragma unroll
        for (int ct = 0; ct < 16; ++ct) {
            const bf16x8 bk = *(const bf16x8*)&sK[ct * 16 + l16][quad * 8];
            sv[ct] = mfma16(aq[i], bk, vzero);
        }
#pragma unroll
        for (int ct = 0; ct < 16; ++ct) {
            const float* bp = &Bias[(h * QL + qr0 + quad * 4) * KL + ct * 16 + l16];
#pragma unroll
            for (int r = 0; r < 4; ++r)
                sv[ct][r] += bp[r * KL] + mterm[ct];
        }
        // softmax: each row's 16 cols-per-ct live on the 16-lane l16 group
        float mx[4] = {-1e30f, -1e30f, -1e30f, -1e30f};
#pragma unroll
        for (int ct = 0; ct < 16; ++ct)
#pragma unroll
            for (int r = 0; r < 4; ++r) mx[r] = fmaxf(mx[r], sv[ct][r]);
#pragma unroll
        for (int off = 1; off < 16; off <<= 1)
#pragma unroll
            for (int r = 0; r < 4; ++r) mx[r] = fmaxf(mx[r], __shfl_xor(mx[r], off, 64));
        float sum[4] = {0.f, 0.f, 0.f, 0.f};
#pragma unroll
        for (int ct = 0; ct < 16; ++ct)
#pragma unroll
            for (int r = 0; r < 4; ++r) {
                const float e = __expf(sv[ct][r] - mx[r]);
                sv[ct][r] = e;
                sum[r] += e;
            }
#pragma unroll
        for (int off = 1; off < 16; off <<= 1)
#pragma unroll
            for (int r = 0; r < 4; ++r) sum[r] += __shfl_xor(sum[r], off, 64);

        // ---- PV in four 64-col chunks via sP (C-layout -> A-layout) ----
        f32x4 o0 = vzero, o1 = vzero;
#pragma unroll
        for (int c = 0; c < 4; ++c) {
#pragma unroll
            for (int cc = 0; cc < 4; ++cc) {
                const int ct = c * 4 + cc;
#pragma unroll
                for (int r = 0; r < 4; ++r)
                    sP[w][quad * 4 + r][cc * 16 + l16] = f2bf(sv[ct][r]);
            }
#pragma unroll
            for (int ks = 0; ks < 2; ++ks) {
                const bf16x8 ap  = *(const bf16x8*)&sP[w][l16][ks * 32 + quad * 8];
                const int kg     = c * 64 + ks * 32 + quad * 8;
                const bf16x8 bv0 = *(const bf16x8*)&sVT[l16][kg];
                const bf16x8 bv1 = *(const bf16x8*)&sVT[16 + l16][kg];
                o0 = mfma16(ap, bv0, o0);
                o1 = mfma16(ap, bv1, o1);
            }
        }
        float rs[4];
#pragma unroll
        for (int r = 0; r < 4; ++r) rs[r] = 1.0f / sum[r];
#pragma unroll
        for (int nt = 0; nt < 2; ++nt) {
            const f32x4 o = nt ? o1 : o0;
#pragma unroll
            for (int r = 0; r < 4; ++r) {
                const int row = qr0 + quad * 4 + r;
                Ows[(s * QL + row) * HD + h * DH + nt * 16 + l16] = f2bf(o[r] * rs[r]);
            }
        }
    }
}

// out[32768,64] = Ows[32768,256](bf16) @ wo[256,64] + bo. 256 blocks x 128 rows.
__launch_bounds__(256, 4)
__global__ void outproj_kernel(const bf16_t* __restrict__ Ows,
                               const float* __restrict__ Wo,
                               const float* __restrict__ Bo,
                               float* __restrict__ Out) {
    const int tid  = threadIdx.x;
    const int lane = tid & 63;
    const int w    = tid >> 6;
    const int quad = lane >> 4;
    const int l16  = lane & 15;
    const int R    = blockIdx.x * 128;

    __shared__ __attribute__((aligned(16))) bf16_t sWoT[CIN][HD + 8];
    __shared__ float sBo[CIN];

    for (int idx = tid; idx < HD * CIN; idx += 256) {
        const int kk = idx >> 6, n = idx & 63;
        sWoT[n][kk] = f2bf(Wo[idx]);
    }
    if (tid < CIN) sBo[tid] = Bo[tid];
    __syncthreads();

    const f32x4 vzero = {0.f, 0.f, 0.f, 0.f};
#pragma unroll
    for (int i = 0; i < 2; ++i) {
        const int mr0 = R + w * 32 + i * 16;
        f32x4 acc[4];
#pragma unroll
        for (int nt = 0; nt < 4; ++nt) acc[nt] = vzero;
#pragma unroll
        for (int ks = 0; ks < 8; ++ks) {
            const bf16x8 a = *(const bf16x8*)&Ows[(mr0 + l16) * HD + ks * 32 + quad * 8];
#pragma unroll
            for (int nt = 0; nt < 4; ++nt) {
                const bf16x8 b = *(const bf16x8*)&sWoT[nt * 16 + l16][ks * 32 + quad * 8];
                acc[nt] = mfma16(a, b, acc[nt]);
            }
        }
#pragma unroll
        for (int nt = 0; nt < 4; ++nt) {
            const float bo = sBo[nt * 16 + l16];
#pragma unroll
            for (int r = 0; r < 4; ++r)
                Out[(mr0 + quad * 4 + r) * CIN + nt * 16 + l16] = acc[nt][r] + bo;
        }
    }
}

extern "C" void kernel_launch(void* const* d_in, const int* in_sizes, int n_in,
                              void* d_out, int out_size, void* d_ws, size_t ws_size,
                              hipStream_t stream) {
    const float* Xq   = (const float*)d_in[0];
    const float* Xkv  = (const float*)d_in[1];
    const float* Mask = (const float*)d_in[2];
    const float* Bias = (const float*)d_in[3];
    const float* Wq   = (const float*)d_in[4];
    const float* Wk   = (const float*)d_in[5];
    const float* Wv   = (const float*)d_in[6];
    const float* Wo   = (const float*)d_in[7];
    const float* Bo   = (const float*)d_in[8];
    float* Out = (float*)d_out;
    bf16_t* Ows = (bf16_t*)d_ws;  // 32768 x 256 bf16 = 16 MB scratch

    attn_h<<<dim3(NH, 128), 256, 0, stream>>>(Xq, Xkv, Mask, Bias, Wq, Wk, Wv, Ows);
    outproj_kernel<<<256, 256, 0, stream>>>(Ows, Wo, Bo, Out);
}

// Round 4
// 197.369 us; speedup vs baseline: 1.7846x; 1.2706x over previous
//
#include <hip/hip_runtime.h>

typedef __bf16 bf16_t;
typedef __bf16 bf16x4_t __attribute__((ext_vector_type(4)));
typedef __bf16 bf16x8 __attribute__((ext_vector_type(8)));
typedef float f32x4 __attribute__((ext_vector_type(4)));

#define NH 8
#define DH 32
#define QL 256
#define KL 256
#define CIN 64
#define HD 256  // NH*DH

__device__ __forceinline__ bf16_t f2bf(float x) { return (bf16_t)x; }

__device__ __forceinline__ f32x4 mfma16(bf16x8 a, bf16x8 b, f32x4 c) {
    return __builtin_amdgcn_mfma_f32_16x16x32_bf16(a, b, c, 0, 0, 0);
}

__device__ __forceinline__ bf16x8 cvt8(const float* __restrict__ p) {
    bf16x8 r;
#pragma unroll
    for (int j = 0; j < 8; ++j) r[j] = f2bf(p[j]);
    return r;
}

// One block per (h, s): 1024 blocks, 256 thr = 4 waves.
// Scores computed as S' = K·Q^T (m=kv, n=q) so that:
//   - bias[q][kv] loads vectorize to float4 (kv = quad*4+r contiguous)
//   - softmax over kv needs only 2 shuffle rounds (xor 16, 32)
//   - 1/sum folds into the P store (per-lane q is fixed at l16)
// Weights are staged via LDS with coalesced float4 loads (no scalar gathers).
__launch_bounds__(256, 2)
__global__ void attn_h(const float* __restrict__ Xq,
                       const float* __restrict__ Xkv,
                       const float* __restrict__ Mask,
                       const float* __restrict__ Bias,
                       const float* __restrict__ Wq,
                       const float* __restrict__ Wk,
                       const float* __restrict__ Wv,
                       bf16_t* __restrict__ Ows) {
    const int h    = blockIdx.x;
    const int s    = blockIdx.y;
    const int tid  = threadIdx.x;
    const int lane = tid & 63;
    const int w    = tid >> 6;
    const int quad = lane >> 4;
    const int l16  = lane & 15;

    // 65 KB total -> 2 blocks/CU. Row strides: odd multiples of 8 bf16
    // (16B-aligned for ds_read_b128, non-pow2 bank spread).
    __shared__ __attribute__((aligned(16))) bf16_t sWT[3][DH][CIN + 8];  // 13824 B (W^T per head: [n=d][k=cin])
    __shared__ __attribute__((aligned(16))) bf16_t sK[KL][DH + 8];       // 20480 B
    __shared__ __attribute__((aligned(16))) bf16_t sVT[DH][KL + 8];      // 16896 B
    __shared__ __attribute__((aligned(16))) bf16_t sQs[4][16][DH + 8];   //  5120 B
    __shared__ __attribute__((aligned(16))) bf16_t sPT[4][16][64 + 8];   //  9216 B
    __shared__ float sMask[KL];                                          //  1024 B

    const float scale = 0.17677669529663687f;  // 1/sqrt(32)
    const f32x4 vzero = {0.f, 0.f, 0.f, 0.f};

    // ---- stage this head's weight slices (coalesced float4) + mask ----
    // Wp slice: rows k=0..63, cols h*32..h*32+31. 512 float4 per matrix.
#pragma unroll
    for (int it = 0; it < 2; ++it) {
        const int idx = it * 256 + tid;
        const int row = idx >> 3;         // k in [0,64)
        const int c4  = (idx & 7) * 4;    // d-col group
        const int ga  = row * HD + h * DH + c4;
        const f32x4 q4 = *(const f32x4*)&Wq[ga];
        const f32x4 k4 = *(const f32x4*)&Wk[ga];
        const f32x4 v4 = *(const f32x4*)&Wv[ga];
#pragma unroll
        for (int j = 0; j < 4; ++j) {
            sWT[0][c4 + j][row] = f2bf(q4[j]);
            sWT[1][c4 + j][row] = f2bf(k4[j]);
            sWT[2][c4 + j][row] = f2bf(v4[j]);
        }
    }
    sMask[tid] = (Mask[s * KL + tid] - 1.0f) * 1.0e9f;
    __syncthreads();

    // ---- weight B-fragments from LDS: B[k=ks*32+quad*8+j][n=nt*16+l16] ----
    bf16x8 bwq[2][2], bwk[2][2], bwv[2][2];
#pragma unroll
    for (int nt = 0; nt < 2; ++nt)
#pragma unroll
        for (int ks = 0; ks < 2; ++ks) {
            bwq[nt][ks] = *(const bf16x8*)&sWT[0][nt * 16 + l16][ks * 32 + quad * 8];
            bwk[nt][ks] = *(const bf16x8*)&sWT[1][nt * 16 + l16][ks * 32 + quad * 8];
            bwv[nt][ks] = *(const bf16x8*)&sWT[2][nt * 16 + l16][ks * 32 + quad * 8];
        }

    // ---- q projection -> B-frags bq[i] (Q enters K·Q^T as the B operand) ----
    // B[k=d][n=q]: lane needs Q[qr0+l16][quad*8..+7] -> LDS round-trip via sQs.
    bf16x8 bq[4];
#pragma unroll
    for (int i = 0; i < 4; ++i) {
        const int r0 = w * 64 + i * 16;
        const float* xp = &Xq[(s * QL + r0 + l16) * CIN + quad * 8];
        const bf16x8 a0 = cvt8(xp);
        const bf16x8 a1 = cvt8(xp + 32);
        f32x4 c0 = vzero, c1 = vzero;
        c0 = mfma16(a0, bwq[0][0], c0);
        c0 = mfma16(a1, bwq[0][1], c0);
        c1 = mfma16(a0, bwq[1][0], c1);
        c1 = mfma16(a1, bwq[1][1], c1);
        // C/D: row(q-local)=quad*4+r, col(d)=nt*16+l16
#pragma unroll
        for (int nt = 0; nt < 2; ++nt) {
            const f32x4 c = nt ? c1 : c0;
#pragma unroll
            for (int r = 0; r < 4; ++r)
                sQs[w][quad * 4 + r][nt * 16 + l16] = f2bf(c[r] * scale);
        }
        // same-wave DS ops in-order: read sees writes above
        bq[i] = *(const bf16x8*)&sQs[w][l16][quad * 8];
    }

    // ---- k, v projections -> sK[kv][d], sVT[d][kv] (wave rows [w*64,+64)) ----
#pragma unroll
    for (int t = 0; t < 4; ++t) {
        const int r0 = w * 64 + t * 16;
        const float* xp = &Xkv[(s * KL + r0 + l16) * CIN + quad * 8];
        const bf16x8 a0 = cvt8(xp);
        const bf16x8 a1 = cvt8(xp + 32);
        f32x4 k0 = vzero, k1 = vzero, v0 = vzero, v1 = vzero;
        k0 = mfma16(a0, bwk[0][0], k0);
        k0 = mfma16(a1, bwk[0][1], k0);
        k1 = mfma16(a0, bwk[1][0], k1);
        k1 = mfma16(a1, bwk[1][1], k1);
        v0 = mfma16(a0, bwv[0][0], v0);
        v0 = mfma16(a1, bwv[0][1], v0);
        v1 = mfma16(a0, bwv[1][0], v1);
        v1 = mfma16(a1, bwv[1][1], v1);
#pragma unroll
        for (int nt = 0; nt < 2; ++nt) {
            const f32x4 kc = nt ? k1 : k0;
            const f32x4 vc = nt ? v1 : v0;
#pragma unroll
            for (int r = 0; r < 4; ++r) {
                const int row = r0 + quad * 4 + r;
                sK[row][nt * 16 + l16]  = f2bf(kc[r]);
                sVT[nt * 16 + l16][row] = f2bf(vc[r]);
            }
        }
    }
    __syncthreads();

    // ---- attention: 4 q-tiles of 16 per wave ----
#pragma unroll 1
    for (int i = 0; i < 4; ++i) {
        const int qr0 = w * 64 + i * 16;
        // S' = K·Q^T: per ct, A = K rows [ct*16, +16), B = bq[i].
        // C/D: row(kv-local)=quad*4+r, col(q)=l16.
        f32x4 sv[16];
#pragma unroll
        for (int ct = 0; ct < 16; ++ct) {
            const bf16x8 ak = *(const bf16x8*)&sK[ct * 16 + l16][quad * 8];
            sv[ct] = mfma16(ak, bq[i], vzero);
        }
        // bias (float4, kv contiguous) + mask (LDS b128 broadcast)
        const float* bbase = &Bias[(h * QL + qr0 + l16) * KL];
#pragma unroll
        for (int ct = 0; ct < 16; ++ct) {
            const f32x4 b4 = *(const f32x4*)&bbase[ct * 16 + quad * 4];
            const f32x4 m4 = *(const f32x4*)&sMask[ct * 16 + quad * 4];
            sv[ct] = sv[ct] + b4 + m4;
        }
        // softmax over kv: 64 per-lane values + xor 16, 32 across quads
        float mx = -1e30f;
#pragma unroll
        for (int ct = 0; ct < 16; ++ct)
#pragma unroll
            for (int r = 0; r < 4; ++r) mx = fmaxf(mx, sv[ct][r]);
        mx = fmaxf(mx, __shfl_xor(mx, 16, 64));
        mx = fmaxf(mx, __shfl_xor(mx, 32, 64));
        float sum = 0.f;
#pragma unroll
        for (int ct = 0; ct < 16; ++ct)
#pragma unroll
            for (int r = 0; r < 4; ++r) {
                const float e = __expf(sv[ct][r] - mx);
                sv[ct][r] = e;
                sum += e;
            }
        sum += __shfl_xor(sum, 16, 64);
        sum += __shfl_xor(sum, 32, 64);
        const float rs = 1.0f / sum;

        // ---- PV in four 64-kv chunks: normalized P^T -> sPT -> A-frags ----
        f32x4 o0 = vzero, o1 = vzero;
#pragma unroll
        for (int c = 0; c < 4; ++c) {
#pragma unroll
            for (int cc = 0; cc < 4; ++cc) {
                const int ct = c * 4 + cc;
                bf16x4_t pv;
#pragma unroll
                for (int r = 0; r < 4; ++r) pv[r] = f2bf(sv[ct][r] * rs);
                *(bf16x4_t*)&sPT[w][l16][cc * 16 + quad * 4] = pv;
            }
#pragma unroll
            for (int ks = 0; ks < 2; ++ks) {
                const bf16x8 ap  = *(const bf16x8*)&sPT[w][l16][ks * 32 + quad * 8];
                const int kg     = c * 64 + ks * 32 + quad * 8;
                const bf16x8 bv0 = *(const bf16x8*)&sVT[l16][kg];
                const bf16x8 bv1 = *(const bf16x8*)&sVT[16 + l16][kg];
                o0 = mfma16(ap, bv0, o0);
                o1 = mfma16(ap, bv1, o1);
            }
        }
        // O tile C/D: row(q-local)=quad*4+r, col(d)=l16 per nt
#pragma unroll
        for (int nt = 0; nt < 2; ++nt) {
            const f32x4 o = nt ? o1 : o0;
#pragma unroll
            for (int r = 0; r < 4; ++r) {
                const int row = qr0 + quad * 4 + r;
                Ows[(s * QL + row) * HD + h * DH + nt * 16 + l16] = f2bf(o[r]);
            }
        }
    }
}

// out[32768,64] = Ows[32768,256](bf16) @ wo[256,64] + bo. 256 blocks x 128 rows.
__launch_bounds__(256, 4)
__global__ void outproj_kernel(const bf16_t* __restrict__ Ows,
                               const float* __restrict__ Wo,
                               const float* __restrict__ Bo,
                               float* __restrict__ Out) {
    const int tid  = threadIdx.x;
    const int lane = tid & 63;
    const int w    = tid >> 6;
    const int quad = lane >> 4;
    const int l16  = lane & 15;
    const int R    = blockIdx.x * 128;

    __shared__ __attribute__((aligned(16))) bf16_t sWoT[CIN][HD + 8];
    __shared__ float sBo[CIN];

    for (int idx = tid; idx < HD * CIN; idx += 256) {
        const int kk = idx >> 6, n = idx & 63;
        sWoT[n][kk] = f2bf(Wo[idx]);
    }
    if (tid < CIN) sBo[tid] = Bo[tid];
    __syncthreads();

    const f32x4 vzero = {0.f, 0.f, 0.f, 0.f};
#pragma unroll 1
    for (int i = 0; i < 2; ++i) {
        const int mr0 = R + w * 32 + i * 16;
        // prefetch all 8 a-frags (independent global loads)
        bf16x8 a[8];
#pragma unroll
        for (int ks = 0; ks < 8; ++ks)
            a[ks] = *(const bf16x8*)&Ows[(mr0 + l16) * HD + ks * 32 + quad * 8];
        f32x4 acc[4];
#pragma unroll
        for (int nt = 0; nt < 4; ++nt) acc[nt] = vzero;
#pragma unroll
        for (int ks = 0; ks < 8; ++ks)
#pragma unroll
            for (int nt = 0; nt < 4; ++nt) {
                const bf16x8 b = *(const bf16x8*)&sWoT[nt * 16 + l16][ks * 32 + quad * 8];
                acc[nt] = mfma16(a[ks], b, acc[nt]);
            }
#pragma unroll
        for (int nt = 0; nt < 4; ++nt) {
            const float bo = sBo[nt * 16 + l16];
#pragma unroll
            for (int r = 0; r < 4; ++r)
                Out[(mr0 + quad * 4 + r) * CIN + nt * 16 + l16] = acc[nt][r] + bo;
        }
    }
}

extern "C" void kernel_launch(void* const* d_in, const int* in_sizes, int n_in,
                              void* d_out, int out_size, void* d_ws, size_t ws_size,
                              hipStream_t stream) {
    const float* Xq   = (const float*)d_in[0];
    const float* Xkv  = (const float*)d_in[1];
    const float* Mask = (const float*)d_in[2];
    const float* Bias = (const float*)d_in[3];
    const float* Wq   = (const float*)d_in[4];
    const float* Wk   = (const float*)d_in[5];
    const float* Wv   = (const float*)d_in[6];
    const float* Wo   = (const float*)d_in[7];
    const float* Bo   = (const float*)d_in[8];
    float* Out = (float*)d_out;
    bf16_t* Ows = (bf16_t*)d_ws;  // 32768 x 256 bf16 = 16 MB scratch

    attn_h<<<dim3(NH, 128), 256, 0, stream>>>(Xq, Xkv, Mask, Bias, Wq, Wk, Wv, Ows);
    outproj_kernel<<<256, 256, 0, stream>>>(Ows, Wo, Bo, Out);
}